// Round 7
// baseline (154.118 us; speedup 1.0000x reference)
//
#include <hip/hip_runtime.h>
#include <math.h>

// Problem constants (from reference setup_inputs)
#define BB 4
#define NN 1000
#define NP 1024          // padded N for MFMA tiles
#define CC 2048
#define TINV (1.0f / 0.07f)
#define CTS 8            // column tiles (NP/128)
#define RTS 16           // row tiles (NP/64)
#define PSLOTS 32        // max positives per (row, 128-col tile); binom(128,1/16)
                         // tail P(>=33) ~ 1e-11 -> safe

// Workspace layout (sim matrix eliminated — fused GEMM+reduce):
//   fnorm : bf16 [BB][NP][CC]   normalized features (rows >= NN zeroed) 16.8 MB
//   Pn    : f32  [BB][CTS][NP]  per-(row, col-tile) sum_neg exp partials
//   Cn    : i32  [BB][CTS][NP]  per-(row, col-tile) positive counts
//   PL    : f32  [BB][CTS][NP][PSLOTS] deferred positive sim values (4 MB)
//   rloss/rpos : f32 [BB][NP]
// R7: R6's fused kernel was latency-bound (MfmaUtil 13%, 1 block/CU, 2
// barriers/K-step with full load latency exposed). Fix: 64x128 tiles ->
// 512 blocks (2/CU, independent barriers overlap) + double-buffered LDS
// with ONE barrier per K-step (prefetch issued after the barrier stays in
// flight across the whole compute phase; drained at the NEXT barrier).
#define FNORM_BYTES ((size_t)BB * NP * CC * 2)
#define PN_BYTES    ((size_t)BB * CTS * NP * 4)
#define PL_BYTES    ((size_t)BB * CTS * NP * PSLOTS * 4)
#define RL_BYTES    ((size_t)BB * NP * 4)

typedef __bf16 bf16x8 __attribute__((ext_vector_type(8)));
typedef float  f32x4  __attribute__((ext_vector_type(4)));

// ---------------------------------------------------------------------------
__device__ __forceinline__ void load_lds16(const void* g, void* l) {
    // async global->LDS, 16B/lane; LDS dest = wave-uniform base + lane*16
    __builtin_amdgcn_global_load_lds(
        (const __attribute__((address_space(1))) unsigned int*)g,
        (__attribute__((address_space(3))) unsigned int*)l, 16, 0, 0);
}

__device__ __forceinline__ float blk_sum(float v, volatile float* lds) {
    int lane = threadIdx.x & 63;
    int wid  = threadIdx.x >> 6;
#pragma unroll
    for (int off = 32; off; off >>= 1) v += __shfl_down(v, off);
    __syncthreads();
    if (lane == 0) lds[wid] = v;
    __syncthreads();
    return lds[0] + lds[1] + lds[2] + lds[3];
}

// ---------------------------------------------------------------------------
// K1: L2-normalize each row, output bf16 into padded [NP x CC] buffer.
// Rows >= NN are zero-filled (so the GEMM needs no bounds checks).
__global__ __launch_bounds__(256) void norm_bf16_kernel(const float* __restrict__ f,
                                                        __bf16* __restrict__ out) {
    __shared__ float lds[4];
    __shared__ float scale_s;
    const int blk = blockIdx.x;              // b*NP + padded row
    const int b = blk >> 10, r = blk & (NP - 1);
    __bf16* dst = out + ((size_t)b * NP + r) * CC;
    const int tid = threadIdx.x;

    if (r >= NN) {                           // zero pad rows: 2048 bf16 = 256 x 16B
        ((uint4*)dst)[tid] = make_uint4(0u, 0u, 0u, 0u);
        return;
    }
    const float* src = f + ((size_t)b * NN + r) * CC;

    float ss = 0.f;
#pragma unroll
    for (int h = 0; h < 2; ++h) {
        float4 v = ((const float4*)src)[tid + h * 256];
        ss += v.x * v.x + v.y * v.y + v.z * v.z + v.w * v.w;
    }
    float tot = blk_sum(ss, lds);
    if (tid == 0) scale_s = 1.0f / fmaxf(sqrtf(tot), 1e-12f);
    __syncthreads();
    const float sc = scale_s;

    float4 v0 = ((const float4*)src)[tid * 2];
    float4 v1 = ((const float4*)src)[tid * 2 + 1];
    bf16x8 o;
    o[0] = (__bf16)(v0.x * sc); o[1] = (__bf16)(v0.y * sc);
    o[2] = (__bf16)(v0.z * sc); o[3] = (__bf16)(v0.w * sc);
    o[4] = (__bf16)(v1.x * sc); o[5] = (__bf16)(v1.y * sc);
    o[6] = (__bf16)(v1.z * sc); o[7] = (__bf16)(v1.w * sc);
    *(bf16x8*)(dst + tid * 8) = o;
}

// ---------------------------------------------------------------------------
// K2 (FUSED): bf16 MFMA GEMM tile + in-register loss reduction.
// 64x128 tile, BK=32, 256 threads (4 waves), wave = 32x64 (2x4 of 16x16x32).
// Double-buffered LDS, one barrier per K-step.
// Epilogue per (row, col-tile): sum_neg exp(s) -> Pn (shfl_xor over q-group),
// pos count -> Cn, deferred pos s values -> PL (LDS-atomic compaction).
// Diagonal excluded by gj != gi; padded cols by gj < NN; padded rows produce
// bounded garbage (sim=0 -> exp=1) that pass 2 never reads.
__global__ __launch_bounds__(256) void fused_gemm_loss(const __bf16* __restrict__ fn,
                                                       const int* __restrict__ tgt,
                                                       float* __restrict__ Pn,
                                                       int* __restrict__ Cn,
                                                       float* __restrict__ PL) {
    __shared__ __bf16 As[2][64 * 32];        // 2 x 4 KB
    __shared__ __bf16 Bs[2][128 * 32];       // 2 x 8 KB
    __shared__ int   ts[NP];                 // 4 KB, padded entries = -1
    __shared__ float Pl[64][2];              // per-row per-wave-col partials
    __shared__ float posl[64][PSLOTS];       // 8 KB pos-value compaction
    __shared__ int   pcl[64];

    const int b  = blockIdx.z;
    const int tI = blockIdx.y * 64;
    const int tJ = blockIdx.x * 128;
    const __bf16* base = fn + (size_t)b * NP * CC;

    const int tid  = threadIdx.x;
    const int wid  = tid >> 6;       // 0..3
    const int lane = tid & 63;
    const int wm   = wid >> 1;       // 0..1  (M half, 32 rows)
    const int wn   = wid & 1;        // 0..1  (N half, 64 cols)
    const int q    = lane >> 4;      // 0..3
    const int ln   = lane & 15;

    // pre-loop LDS init (covered by the first K-loop barrier)
    const int* t = tgt + (size_t)b * NN;
    for (int j = tid; j < NP; j += 256) ts[j] = (j < NN) ? t[j] : -1;
    if (tid < 64) pcl[tid] = 0;

    // staging: A tile 64x32 = 4 KB (1 issue/wave), B tile 128x32 = 8 KB (2)
    const int srow  = tid >> 2;                     // 0..63
    const int selem = (tid & 3) * 8;                // bf16 elem offset in row
    const __bf16* gA  = base + (size_t)(tI + srow) * CC + selem;
    const __bf16* gB0 = base + (size_t)(tJ + srow) * CC + selem;
    const __bf16* gB1 = base + (size_t)(tJ + 64 + srow) * CC + selem;
    const int ldsoff = wid * 512;    // wave-uniform: wid*16 rows * 32 elems

    f32x4 acc[2][4] = {};

    // prefetch k=0 into buffer 0
    load_lds16(gA, &As[0][ldsoff]);
    load_lds16(gB0, &Bs[0][ldsoff]);
    load_lds16(gB1, &Bs[0][2048 + ldsoff]);

    int p = 0;
    for (int k0 = 32; k0 <= CC; k0 += 32) {
        __syncthreads();             // drains loads into buf p; separates
                                     // previous compute on buf p^1
        if (k0 < CC) {               // prefetch next step into buf p^1 —
            load_lds16(gA + k0, &As[p ^ 1][ldsoff]);          // stays in
            load_lds16(gB0 + k0, &Bs[p ^ 1][ldsoff]);         // flight through
            load_lds16(gB1 + k0, &Bs[p ^ 1][2048 + ldsoff]);  // this compute
        }
        bf16x8 af[2], bf[4];
#pragma unroll
        for (int mt = 0; mt < 2; ++mt)
            af[mt] = *(const bf16x8*)&As[p][(wm * 32 + mt * 16 + ln) * 32 + q * 8];
#pragma unroll
        for (int nt = 0; nt < 4; ++nt)
            bf[nt] = *(const bf16x8*)&Bs[p][(wn * 64 + nt * 16 + ln) * 32 + q * 8];
#pragma unroll
        for (int mt = 0; mt < 2; ++mt)
#pragma unroll
            for (int nt = 0; nt < 4; ++nt)
                acc[mt][nt] = __builtin_amdgcn_mfma_f32_16x16x32_bf16(
                    af[mt], bf[nt], acc[mt][nt], 0, 0, 0);
        p ^= 1;
    }

    // ---------------- epilogue: in-register reduction ----------------
    // C/D layout (m89-verified): col = ln, row = q*4 + r per 16x16 block.
    float sneg[8];                   // indexed [mt*4+r]
#pragma unroll
    for (int k = 0; k < 8; ++k) sneg[k] = 0.f;

#pragma unroll
    for (int mt = 0; mt < 2; ++mt) {
        int gi4[4], tr4[4];
#pragma unroll
        for (int r = 0; r < 4; ++r) {
            const int rloc = wm * 32 + mt * 16 + q * 4 + r;
            gi4[r] = tI + rloc;
            tr4[r] = ts[tI + rloc];
        }
#pragma unroll
        for (int nt = 0; nt < 4; ++nt) {
            const int cloc = wn * 64 + nt * 16 + ln;
            const int gj   = tJ + cloc;
            const int tc   = ts[gj];
            const bool jvalid = (gj < NN);
#pragma unroll
            for (int r = 0; r < 4; ++r) {
                const float s = acc[mt][nt][r] * TINV;
                if (jvalid && gj != gi4[r]) {
                    if (tc == tr4[r]) {
                        const int rloc = wm * 32 + mt * 16 + q * 4 + r;
                        int slot = atomicAdd(&pcl[rloc], 1);
                        if (slot < PSLOTS) posl[rloc][slot] = s;
                    } else {
                        sneg[mt * 4 + r] += __expf(s);
                    }
                }
            }
        }
    }
    // reduce sneg across the 16 lanes of each q-group (covers wave's 64 cols)
#pragma unroll
    for (int m = 1; m < 16; m <<= 1)
#pragma unroll
        for (int k = 0; k < 8; ++k) sneg[k] += __shfl_xor(sneg[k], m);
    if (ln == 0) {
#pragma unroll
        for (int mt = 0; mt < 2; ++mt)
#pragma unroll
            for (int r = 0; r < 4; ++r)
                Pl[wm * 32 + mt * 16 + q * 4 + r][wn] = sneg[mt * 4 + r];
    }
    __syncthreads();

    // ---------------- write-out ----------------
    const size_t tileo = ((size_t)(b * CTS + blockIdx.x)) * NP + tI;
    if (tid < 64) {
        Pn[tileo + tid] = Pl[tid][0] + Pl[tid][1];
        Cn[tileo + tid] = min(pcl[tid], PSLOTS);
    }
    // pos lists: 64 rows x 32 slots = 512 float4; 2 per thread
    {
        const float4* src = (const float4*)&posl[0][0];
        float4* dst = (float4*)&PL[tileo * PSLOTS];
        dst[tid]       = src[tid];
        dst[tid + 256] = src[tid + 256];
    }
}

// ---------------------------------------------------------------------------
// K3: pass 2 — one THREAD per row. S_i = sum of 8 col-tile partials; then
// deferred pos terms: sum log(exp(s)+S) - s; plus (N-p)*log(1+S).
// (exp(sim_ii) never enters S — avoids the exp(14.3)=1.6e6 cancellation.)
__global__ __launch_bounds__(256) void rowloss2_kernel(const float* __restrict__ Pn,
                                                       const int* __restrict__ Cn,
                                                       const float* __restrict__ PL,
                                                       float* __restrict__ rloss,
                                                       float* __restrict__ rpos) {
    const int b = blockIdx.y;
    const int i = blockIdx.x * 256 + threadIdx.x;
    if (i >= NN) return;

    float S = 0.f;
#pragma unroll
    for (int ct = 0; ct < CTS; ++ct)
        S += Pn[(size_t)(b * CTS + ct) * NP + i];

    float term = 0.f, p = 0.f;
#pragma unroll
    for (int ct = 0; ct < CTS; ++ct) {
        const size_t o = (size_t)(b * CTS + ct) * NP + i;
        const int c = Cn[o];
        p += (float)c;
        const float* pl = &PL[o * PSLOTS];
        for (int k = 0; k < c; ++k) {
            const float s = pl[k];
            term += __logf(__expf(s) + S) - s;
        }
    }
    rloss[b * NP + i] = term + ((float)NN - p) * __logf(1.f + S);
    rpos [b * NP + i] = p;
}

// ---------------------------------------------------------------------------
// K4: reduce per-row partials and combine exactly as the reference does.
__global__ __launch_bounds__(256) void final_kernel(const float* __restrict__ rloss,
                                                    const float* __restrict__ rpos,
                                                    float* __restrict__ out) {
    __shared__ float lds[4];
    float total = 0.f, np = 0.f;
    for (int b = 0; b < BB; ++b) {
        float l = 0.f, p = 0.f;
        for (int i = threadIdx.x; i < NN; i += 256) {
            l += rloss[b * NP + i];
            p += rpos [b * NP + i];
        }
        float ls = blk_sum(l, lds);
        float ps = blk_sum(p, lds);
        if (ps > 0.f) { total += ls / (ps + 1e-6f); np += 1.f; }
    }
    if (threadIdx.x == 0)
        out[0] = (np > 0.f) ? 0.1f * total / np : 0.1f * 0.1f;
}

// ---------------------------------------------------------------------------
extern "C" void kernel_launch(void* const* d_in, const int* in_sizes, int n_in,
                              void* d_out, int out_size, void* d_ws, size_t ws_size,
                              hipStream_t stream) {
    const float* feat = (const float*)d_in[0];
    const int*   tgt  = (const int*)d_in[1];
    char* ws = (char*)d_ws;
    __bf16* fnorm = (__bf16*)ws;                               ws += FNORM_BYTES;
    float*  Pn    = (float*)ws;                                ws += PN_BYTES;
    int*    Cn    = (int*)ws;                                  ws += PN_BYTES;
    float*  PL    = (float*)ws;                                ws += PL_BYTES;
    float*  rloss = (float*)ws;                                ws += RL_BYTES;
    float*  rpos  = (float*)ws;

    norm_bf16_kernel<<<dim3(BB * NP), 256, 0, stream>>>(feat, fnorm);
    fused_gemm_loss<<<dim3(CTS, RTS, BB), 256, 0, stream>>>(fnorm, tgt, Pn, Cn, PL);
    rowloss2_kernel<<<dim3(NP / 256, BB), 256, 0, stream>>>(Pn, Cn, PL, rloss, rpos);
    final_kernel<<<1, 256, 0, stream>>>(rloss, rpos, (float*)d_out);
}

// Round 8
// 116.081 us; speedup vs baseline: 1.3277x; 1.3277x over previous
//
#include <hip/hip_runtime.h>
#include <math.h>

// Problem constants (from reference setup_inputs)
#define BB 4
#define NN 1000
#define NP 1024          // padded N for MFMA tiles
#define CC 2048
#define TINV (1.0f / 0.07f)
#define BK 64

// Workspace layout:
//   fnorm : bf16 [BB][NP][CC]  normalized features (rows >= NN zeroed) 16.8 MB
//   simb  : bf16 [2*BB][NP][NP] split-K=2 sim partials (bz = 2*b+kz)   16.8 MB
//   rloss/rpos : f32 [BB][NP]
// No atomics anywhere (R2: 8000 same-line device atomicAdds = 110 us).
// Split-K=2 (R4): 512 blocks = 2 independent blocks/CU.
// R8: (a) statically dual-buffered K-loop — distinct __shared__ objects so
//     AA doesn't force vmcnt(0) before ds_read (R7's dynamic-index dbuf
//     regressed, likely this hazard); one barrier/step, prefetch in flight
//     across the whole compute phase. (b) bf16 sim: halves sim write+read.
#define FNORM_BYTES ((size_t)BB * NP * CC * 2)
#define SIMB_BYTES  ((size_t)2 * BB * NP * NP * 2)
#define RL_BYTES    ((size_t)BB * NP * 4)

typedef __bf16 bf16x8 __attribute__((ext_vector_type(8)));
typedef float  f32x4  __attribute__((ext_vector_type(4)));
typedef float  f32x16 __attribute__((ext_vector_type(16)));

// ---------------------------------------------------------------------------
__device__ __forceinline__ void load_lds16(const void* g, void* l) {
    // async global->LDS, 16B/lane; LDS dest = wave-uniform base + lane*16
    __builtin_amdgcn_global_load_lds(
        (const __attribute__((address_space(1))) unsigned int*)g,
        (__attribute__((address_space(3))) unsigned int*)l, 16, 0, 0);
}

__device__ __forceinline__ float blk_sum(float v, volatile float* lds) {
    int lane = threadIdx.x & 63;
    int wid  = threadIdx.x >> 6;
#pragma unroll
    for (int off = 32; off; off >>= 1) v += __shfl_down(v, off);
    __syncthreads();
    if (lane == 0) lds[wid] = v;
    __syncthreads();
    return lds[0] + lds[1] + lds[2] + lds[3];
}

__device__ __forceinline__ float wave_sum(float v) {
#pragma unroll
    for (int off = 32; off; off >>= 1) v += __shfl_down(v, off);
    return __shfl(v, 0);
}

// ---------------------------------------------------------------------------
// K1: L2-normalize each row, output bf16 into padded [NP x CC] buffer.
// Rows >= NN are zero-filled (so the GEMM needs no bounds checks).
__global__ __launch_bounds__(256) void norm_bf16_kernel(const float* __restrict__ f,
                                                        __bf16* __restrict__ out) {
    __shared__ float lds[4];
    __shared__ float scale_s;
    const int blk = blockIdx.x;              // b*NP + padded row
    const int b = blk >> 10, r = blk & (NP - 1);
    __bf16* dst = out + ((size_t)b * NP + r) * CC;
    const int tid = threadIdx.x;

    if (r >= NN) {                           // zero pad rows: 2048 bf16 = 256 x 16B
        ((uint4*)dst)[tid] = make_uint4(0u, 0u, 0u, 0u);
        return;
    }
    const float* src = f + ((size_t)b * NN + r) * CC;

    float ss = 0.f;
#pragma unroll
    for (int h = 0; h < 2; ++h) {
        float4 v = ((const float4*)src)[tid + h * 256];
        ss += v.x * v.x + v.y * v.y + v.z * v.z + v.w * v.w;
    }
    float tot = blk_sum(ss, lds);
    if (tid == 0) scale_s = 1.0f / fmaxf(sqrtf(tot), 1e-12f);
    __syncthreads();
    const float sc = scale_s;

    float4 v0 = ((const float4*)src)[tid * 2];
    float4 v1 = ((const float4*)src)[tid * 2 + 1];
    bf16x8 o;
    o[0] = (__bf16)(v0.x * sc); o[1] = (__bf16)(v0.y * sc);
    o[2] = (__bf16)(v0.z * sc); o[3] = (__bf16)(v0.w * sc);
    o[4] = (__bf16)(v1.x * sc); o[5] = (__bf16)(v1.y * sc);
    o[6] = (__bf16)(v1.z * sc); o[7] = (__bf16)(v1.w * sc);
    *(bf16x8*)(dst + tid * 8) = o;
}

// ---------------------------------------------------------------------------
// K2: simb[2b+kz] = bf16( partial (fn[b] * fn[b]^T) * (1/T) ) over K-half kz.
// 256 threads (4 waves), tile 128x128, BK=64; wave = 64x64 via 2x2 of
// v_mfma_f32_32x32x16_bf16. LDS XOR-swizzled: (row, chunk c) at slot
// c^(row&7), applied on the GLOBAL side of global_load_lds (R5-proven).
// Static dual buffers As0/As1, Bs0/Bs1; one barrier per K-step; prefetch
// issued right after the barrier stays in flight through the compute phase.
__global__ __launch_bounds__(256) void simgemm_mfma(const __bf16* __restrict__ fn,
                                                    __bf16* __restrict__ simb) {
    __shared__ __bf16 As0[128 * BK], As1[128 * BK];   // 16 KB each
    __shared__ __bf16 Bs0[128 * BK], Bs1[128 * BK];   // total 64 KB

    const int bz = blockIdx.z;        // 0..2*BB-1
    const int b  = bz >> 1;
    const int kbeg = (bz & 1) * (CC / 2);
    const int tI = blockIdx.y * 128;
    const int tJ = blockIdx.x * 128;
    const __bf16* base = fn + (size_t)b * NP * CC;
    __bf16* S = simb + (size_t)bz * NP * NP;

    const int tid  = threadIdx.x;
    const int wid  = tid >> 6;        // 0..3
    const int lane = tid & 63;
    const int wm   = wid >> 1;        // 0..1  (M half, 64 rows)
    const int wn   = wid & 1;         // 0..1  (N half, 64 cols)
    const int ln32 = lane & 31;
    const int kh   = lane >> 5;       // k-half within frag (0..1)
    const int sw   = ln32 & 7;        // frag-read swizzle key

    // staging: issue r covers rows r*32 + (tid>>3); lane carries swizzled chunk
    const int srow   = tid >> 3;                    // 0..31
    const int schunk = (tid & 7) ^ (srow & 7);      // XOR swizzle, global side
    const __bf16* gA = base + (size_t)(tI + srow) * CC + kbeg + schunk * 8;
    const __bf16* gB = base + (size_t)(tJ + srow) * CC + kbeg + schunk * 8;
    const int wvoff = wid * 8 * BK;                 // wave-uniform LDS base

    f32x16 acc[2][2] = {};

#define STAGE(k0, A, B)                                                      \
    {                                                                        \
        _Pragma("unroll")                                                    \
        for (int r = 0; r < 4; ++r)                                          \
            load_lds16(gA + (k0) + (size_t)r * 32 * CC, (A) + r * 32 * BK + wvoff); \
        _Pragma("unroll")                                                    \
        for (int r = 0; r < 4; ++r)                                          \
            load_lds16(gB + (k0) + (size_t)r * 32 * CC, (B) + r * 32 * BK + wvoff); \
    }

#define COMPUTE(A, B)                                                        \
    {                                                                        \
        _Pragma("unroll")                                                    \
        for (int kc = 0; kc < 4; ++kc) {                                     \
            const int co = ((kc * 2 + kh) ^ sw) * 8;                         \
            bf16x8 a0 = *(const bf16x8*)&(A)[(wm * 64      + ln32) * BK + co]; \
            bf16x8 a1 = *(const bf16x8*)&(A)[(wm * 64 + 32 + ln32) * BK + co]; \
            bf16x8 b0 = *(const bf16x8*)&(B)[(wn * 64      + ln32) * BK + co]; \
            bf16x8 b1 = *(const bf16x8*)&(B)[(wn * 64 + 32 + ln32) * BK + co]; \
            acc[0][0] = __builtin_amdgcn_mfma_f32_32x32x16_bf16(a0, b0, acc[0][0], 0, 0, 0); \
            acc[0][1] = __builtin_amdgcn_mfma_f32_32x32x16_bf16(a0, b1, acc[0][1], 0, 0, 0); \
            acc[1][0] = __builtin_amdgcn_mfma_f32_32x32x16_bf16(a1, b0, acc[1][0], 0, 0, 0); \
            acc[1][1] = __builtin_amdgcn_mfma_f32_32x32x16_bf16(a1, b1, acc[1][1], 0, 0, 0); \
        }                                                                    \
    }

    STAGE(0, As0, Bs0);
#pragma unroll 1
    for (int k0 = 0; k0 < CC / 2; k0 += 2 * BK) {   // 8 outer = 16 K-steps
        __syncthreads();                            // drains loads into buf0
        if (k0 + BK < CC / 2) STAGE(k0 + BK, As1, Bs1);
        COMPUTE(As0, Bs0);
        __syncthreads();                            // drains loads into buf1
        if (k0 + 2 * BK < CC / 2) STAGE(k0 + 2 * BK, As0, Bs0);
        COMPUTE(As1, Bs1);
    }
#undef STAGE
#undef COMPUTE

    // C/D layout (m74/m101-verified): col = lane&31,
    // row = (reg&3) + 8*(reg>>2) + 4*(lane>>5).  bf16 store: lanes 0..31
    // write one contiguous 64B segment per row -> coalesces fine.
#pragma unroll
    for (int at = 0; at < 2; ++at) {
#pragma unroll
        for (int bt = 0; bt < 2; ++bt) {
            const int col = tJ + wn * 64 + bt * 32 + ln32;
#pragma unroll
            for (int r = 0; r < 16; ++r) {
                const int row = tI + wm * 64 + at * 32 + (r & 3) + 8 * (r >> 2) + 4 * kh;
                S[(size_t)row * NP + col] = (__bf16)(acc[at][bt][r] * TINV);
            }
        }
    }
}

// ---------------------------------------------------------------------------
// K3: per-row masked reductions, one WAVE per row (4 rows/block).
// Row loss-mat sum = (N - p_i)*log(1+S_i) + sum_{pos j}[log(exp(s)+S_i) - s]
// Diagonal excluded by masking j==i (NOT by subtracting exp(sim_ii):
// exp(1/0.07)=1.6e6 vs S_i~1e3 would be catastrophic cancellation).
// bf16 split-K partials summed ONCE into an LDS row cache; pass 2 reads LDS.
__global__ __launch_bounds__(256) void rowloss_kernel(const __bf16* __restrict__ simb,
                                                      const int* __restrict__ tgt,
                                                      float* __restrict__ rloss,
                                                      float* __restrict__ rpos) {
    __shared__ __align__(16) int ts[NN];
    __shared__ float rowv[4][NP];                  // 16 KB row cache
    const int b = blockIdx.y;
    const int wid = threadIdx.x >> 6, lane = threadIdx.x & 63;
    const int* t = tgt + (size_t)b * NN;
    for (int j = threadIdx.x; j < NN; j += 256) ts[j] = t[j];
    __syncthreads();

    const int i = blockIdx.x * 4 + wid;            // grid.x = 250 -> i < 1000
    const __bf16* r0 = simb + (size_t)(2 * b) * NP * NP + (size_t)i * NP;
    const __bf16* r1 = r0 + (size_t)NP * NP;
    const int ti = ts[i];

    float sneg = 0.f, pcnt = 0.f;
    for (int g = lane; g < NN / 8; g += 64) {      // 125 bf16x8 groups = 1000 cols
        bf16x8 va = ((const bf16x8*)r0)[g];
        bf16x8 vb = ((const bf16x8*)r1)[g];
        float v[8];
#pragma unroll
        for (int k = 0; k < 8; ++k) v[k] = (float)va[k] + (float)vb[k];
        *(f32x4*)&rowv[wid][g * 8]     = *(f32x4*)&v[0];
        *(f32x4*)&rowv[wid][g * 8 + 4] = *(f32x4*)&v[4];
        const int jb = g * 8;
#pragma unroll
        for (int k = 0; k < 8; ++k) {
            const int j = jb + k;
            if (j != i) {
                if (ts[j] == ti) pcnt += 1.f;
                else             sneg += __expf(v[k]);
            }
        }
    }
    const float Sv = wave_sum(sneg);
    const float p  = wave_sum(pcnt);

    float term = 0.f;                              // pass 2: LDS only (wave-private)
    for (int g = lane; g < NN / 8; g += 64) {
        const int jb = g * 8;
        float v[8];
        *(f32x4*)&v[0] = *(const f32x4*)&rowv[wid][jb];
        *(f32x4*)&v[4] = *(const f32x4*)&rowv[wid][jb + 4];
#pragma unroll
        for (int k = 0; k < 8; ++k) {
            const int j = jb + k;
            if (j != i && ts[j] == ti)
                term += __logf(__expf(v[k]) + Sv) - v[k];
        }
    }
    const float tt = wave_sum(term);
    if (lane == 0) {
        rloss[b * NP + i] = tt + ((float)NN - p) * __logf(1.f + Sv);
        rpos [b * NP + i] = p;
    }
}

// ---------------------------------------------------------------------------
// K4: reduce per-row partials and combine exactly as the reference does.
__global__ __launch_bounds__(256) void final_kernel(const float* __restrict__ rloss,
                                                    const float* __restrict__ rpos,
                                                    float* __restrict__ out) {
    __shared__ float lds[4];
    float total = 0.f, np = 0.f;
    for (int b = 0; b < BB; ++b) {
        float l = 0.f, p = 0.f;
        for (int i = threadIdx.x; i < NN; i += 256) {
            l += rloss[b * NP + i];
            p += rpos [b * NP + i];
        }
        float ls = blk_sum(l, lds);
        float ps = blk_sum(p, lds);
        if (ps > 0.f) { total += ls / (ps + 1e-6f); np += 1.f; }
    }
    if (threadIdx.x == 0)
        out[0] = (np > 0.f) ? 0.1f * total / np : 0.1f * 0.1f;
}

// ---------------------------------------------------------------------------
extern "C" void kernel_launch(void* const* d_in, const int* in_sizes, int n_in,
                              void* d_out, int out_size, void* d_ws, size_t ws_size,
                              hipStream_t stream) {
    const float* feat = (const float*)d_in[0];
    const int*   tgt  = (const int*)d_in[1];
    char* ws = (char*)d_ws;
    __bf16* fnorm = (__bf16*)ws;                  ws += FNORM_BYTES;
    __bf16* simb  = (__bf16*)ws;                  ws += SIMB_BYTES;
    float*  rloss = (float*)ws;                   ws += RL_BYTES;
    float*  rpos  = (float*)ws;

    norm_bf16_kernel<<<dim3(BB * NP), 256, 0, stream>>>(feat, fnorm);
    simgemm_mfma<<<dim3(NP / 128, NP / 128, 2 * BB), 256, 0, stream>>>(fnorm, simb);
    rowloss_kernel<<<dim3(NN / 4, BB), 256, 0, stream>>>(simb, tgt, rloss, rpos);
    final_kernel<<<1, 256, 0, stream>>>(rloss, rpos, (float*)d_out);
}